// Round 2
// baseline (593.588 us; speedup 1.0000x reference)
//
#include <hip/hip_runtime.h>

// ESN recurrence, MI355X — TWO consumer waves + spin-mailbox revision.
//
// THEORY (this round): 615 cyc/step on one consumer wave = quarter-rate
// transcendental issue (16 trans/step, wave64 ~16 cyc each ≈ 256 cyc) +
// full-rate VALU (~90) + shfl->edge->shfl serial chain (~200). Fix: split
// the 512-element ring across TWO consumer waves (4 elems/lane) on
// different SIMDs — per-wave trans issue halves, stores halve, and the two
// cut-point edge values are exchanged per step via a tagged LDS mailbox
// (parity double-buffered, spin-polled) with NO workgroup barrier, so the
// 64-phase producer cadence is unchanged. Interior elems + intra-wave
// shfls overlap the mailbox round trip.
//
// ubuf swizzle removed: consumer reads are contiguous 1KB/wave (bank
// floor), producer writes consecutive-r (conflict-free). Phase barriers
// stay lgkm-only (consumer output stores remain in flight).

#define B_DIM 128
#define T_DIM 1024
#define D_DIM 8
#define R_DIM 512
#define NT    16            // timesteps per phase
#define NPHASE 64           // covers 1023 steps (last phase has 15)
#define HALF  256           // reservoir elems per consumer wave

#define SC   2.8853900817779268f   // 2*log2(e), folded into W and betas
#define BP_S (0.15f * SC)          // coeff on s[r+1], scaled
#define BM_S (0.85f * SC)          // coeff on s[r-1], scaled

__device__ __forceinline__ float esn_step(float L, float R, float u) {
    // pre' = 2log2e * (0.85 L + 0.15 R + u_raw); u already scaled.
    const float pre = fmaf(BM_S, L, fmaf(BP_S, R, u));
#if __has_builtin(__builtin_amdgcn_exp2f) && __has_builtin(__builtin_amdgcn_rcpf)
    const float e = __builtin_amdgcn_exp2f(pre);
    return fmaf(-2.0f, __builtin_amdgcn_rcpf(e + 1.0f), 1.0f);
#else
    const float e = exp2f(pre);
    return 1.0f - 2.0f / (e + 1.0f);
#endif
}

__device__ __forceinline__ void barrier_lds_only() {
    // LDS drain + barrier WITHOUT vmcnt(0): pending global stores stay in
    // flight across the barrier.
    asm volatile("s_waitcnt lgkmcnt(0)\n\ts_barrier" ::: "memory");
}

__global__ __launch_bounds__(512, 1) void esn_kernel(const float* __restrict__ x,
                                                     const float* __restrict__ W,
                                                     float* __restrict__ out) {
    __shared__ float ubuf[2][NT][R_DIM];            // u ring, 64 KB, plain layout
    // mailbox[wave][parity][e]: e=0 -> first elem of arc (r=256w, lane0 n0),
    //                           e=1 -> last  elem of arc (r=256w+255, lane63 n3)
    // packed {tag:int (hi32), value:f32 bits (lo32)}; single b64 write = atomic enough.
    __shared__ unsigned long long mbox[2][2][2];

    const int b   = blockIdx.x;
    const int tid = threadIdx.x;
    const float* xb = x + (size_t)b * T_DIM * D_DIM;

    // ---- Own W row (scaled) in registers for the prologue.
    const float4 wa = *(const float4*)(W + tid * D_DIM);
    const float4 wc = *(const float4*)(W + tid * D_DIM + 4);
    const float w0 = wa.x * SC, w1 = wa.y * SC, w2 = wa.z * SC, w3 = wa.w * SC;
    const float w4 = wc.x * SC, w5 = wc.y * SC, w6 = wc.z * SC, w7 = wc.w * SC;

    // ---- Mailbox prefill: tag=-1, value=0 (initial state is all zeros).
    if (tid < 8) ((unsigned long long*)mbox)[tid] = 0xFFFFFFFF00000000ull;

    // ---- Prologue: all 512 threads fill phase 0 (t = 1..16), r = tid.
#pragma unroll
    for (int j = 0; j < NT; ++j) {
        const float4 xa = *(const float4*)(xb + (j + 1) * D_DIM);
        const float4 xc = *(const float4*)(xb + (j + 1) * D_DIM + 4);
        float u = xa.x * w0;
        u = fmaf(xa.y, w1, u); u = fmaf(xa.z, w2, u); u = fmaf(xa.w, w3, u);
        u = fmaf(xc.x, w4, u); u = fmaf(xc.y, w5, u);
        u = fmaf(xc.z, w6, u); u = fmaf(xc.w, w7, u);
        ubuf[0][j][tid] = u;
    }
    __syncthreads();  // one full barrier before the loop (no stores pending yet)

    const int wid  = tid >> 6;
    const int lane = tid & 63;

    if (wid < 2) {
        // ================= consumers (2 waves, 4 elems/lane) =================
        asm volatile("s_setprio 3" ::: "memory");
        const int w  = wid;
        const int ow = 1 - wid;
        const int lp = (lane + 63) & 63;   // left lane (source of elem0's L)
        const int ln = (lane + 1) & 63;    // right lane (source of elem3's R)

        float s0 = 0.0f, s1 = 0.0f, s2 = 0.0f, s3 = 0.0f;
        float* op = out + (size_t)b * T_DIM * R_DIM + w * HALF + lane * 4;

        int i = 0;  // global step index (tag)
        for (int k = 0; k < NPHASE; ++k) {
            const float* ub = &ubuf[k & 1][0][w * HALF + lane * 4];
            const int steps = (k == NPHASE - 1) ? (1023 - NT * (NPHASE - 1)) : NT;
            float4 ua = *(const float4*)ub;
            for (int tl = 0; tl < steps; ++tl, ++i) {
                // prefetch next step's u (off the critical path)
                const int tn = (tl + 1 < steps) ? (tl + 1) : tl;
                const float4 na = *(const float4*)(ub + (size_t)tn * R_DIM);

                // intra-wave neighbor exchange (issued early; latency overlaps)
                const float Lr = __shfl(s3, lp, 64);  // left lane's elem3 = r-1
                const float Rr = __shfl(s0, ln, 64);  // right lane's elem0 = r+4

                // interior elements: independent of mailbox/shfl
                const float n1 = esn_step(s0, s2, ua.y);
                const float n2 = esn_step(s1, s3, ua.z);

                // cross-wave edges: poll other wave's step-(i-1) mailbox
                const int pp = (i + 1) & 1;  // == (i-1) & 1
                unsigned long long ea, eb;
                do {
                    ea = *(volatile const unsigned long long*)&mbox[ow][pp][1];
                    eb = *(volatile const unsigned long long*)&mbox[ow][pp][0];
                } while ((int)(ea >> 32) != i - 1 || (int)(eb >> 32) != i - 1);
                const float L = (lane == 0)  ? __uint_as_float((unsigned)ea) : Lr;
                const float R = (lane == 63) ? __uint_as_float((unsigned)eb) : Rr;

                const float n0 = esn_step(L,  s1, ua.x);
                const float n3 = esn_step(s2, R,  ua.w);

                // publish my edges for the other wave's step i+1
                if (lane == 0)
                    *(volatile unsigned long long*)&mbox[w][i & 1][0] =
                        ((unsigned long long)(unsigned)i << 32) | __float_as_uint(n0);
                if (lane == 63)
                    *(volatile unsigned long long*)&mbox[w][i & 1][1] =
                        ((unsigned long long)(unsigned)i << 32) | __float_as_uint(n3);

                // fire-and-forget, coalesced 1 KB/wave
                *(float4*)op = make_float4(n0, n1, n2, n3);
                op += R_DIM;

                s0 = n0; s1 = n1; s2 = n2; s3 = n3;
                ua = na;
            }
            barrier_lds_only();
        }
    } else {
        // ================= producers (6 waves) =================
        // Fixed r per thread: W row in registers, zero LDS reads steady-state.
        // Waves 2-3 (pid < 128) additionally own r = pid + 384.
        asm volatile("s_setprio 0" ::: "memory");
        const int pid = tid - 128;  // 0..383
        const float4 pa = *(const float4*)(W + pid * D_DIM);
        const float4 pc = *(const float4*)(W + pid * D_DIM + 4);
        const float a0 = pa.x * SC, a1 = pa.y * SC, a2 = pa.z * SC, a3 = pa.w * SC;
        const float a4 = pc.x * SC, a5 = pc.y * SC, a6 = pc.z * SC, a7 = pc.w * SC;

        const bool dual = (pid < 128);   // waves 2,3: wave-uniform
        float b0 = 0.f, b1 = 0.f, b2 = 0.f, b3 = 0.f,
              b4 = 0.f, b5 = 0.f, b6 = 0.f, b7 = 0.f;
        if (dual) {
            const float4 qa = *(const float4*)(W + (pid + 384) * D_DIM);
            const float4 qc = *(const float4*)(W + (pid + 384) * D_DIM + 4);
            b0 = qa.x * SC; b1 = qa.y * SC; b2 = qa.z * SC; b3 = qa.w * SC;
            b4 = qc.x * SC; b5 = qc.y * SC; b6 = qc.z * SC; b7 = qc.w * SC;
        }

        for (int k = 0; k < NPHASE; ++k) {
            if (k + 1 < NPHASE) {
                const int tb = NT * (k + 1) + 1;      // first t of next phase
                float* dst = &ubuf[(k + 1) & 1][0][0];
#pragma unroll
                for (int tl = 0; tl < NT; ++tl) {
                    const int t = tb + tl;
                    if (t < T_DIM) {
                        // wave-uniform address: one 32B line, broadcast
                        const float4 xa = *(const float4*)(xb + t * D_DIM);
                        const float4 xc = *(const float4*)(xb + t * D_DIM + 4);
                        float u = xa.x * a0;
                        u = fmaf(xa.y, a1, u); u = fmaf(xa.z, a2, u);
                        u = fmaf(xa.w, a3, u); u = fmaf(xc.x, a4, u);
                        u = fmaf(xc.y, a5, u); u = fmaf(xc.z, a6, u);
                        u = fmaf(xc.w, a7, u);
                        dst[tl * R_DIM + pid] = u;
                        if (dual) {
                            float u2 = xa.x * b0;
                            u2 = fmaf(xa.y, b1, u2); u2 = fmaf(xa.z, b2, u2);
                            u2 = fmaf(xa.w, b3, u2); u2 = fmaf(xc.x, b4, u2);
                            u2 = fmaf(xc.y, b5, u2); u2 = fmaf(xc.z, b6, u2);
                            u2 = fmaf(xc.w, b7, u2);
                            dst[tl * R_DIM + pid + 384] = u2;
                        }
                    }
                }
            }
            barrier_lds_only();
        }
    }

    // Reference's final timestep is all zeros (d_out is poisoned 0xAA).
    out[(size_t)b * T_DIM * R_DIM + (size_t)(T_DIM - 1) * R_DIM + tid] = 0.0f;
}

extern "C" void kernel_launch(void* const* d_in, const int* in_sizes, int n_in,
                              void* d_out, int out_size, void* d_ws, size_t ws_size,
                              hipStream_t stream) {
    const float* x = (const float*)d_in[0];   // [B, T, D] fp32
    const float* W = (const float*)d_in[1];   // [R, D] fp32
    float* out = (float*)d_out;               // [B, T, R] fp32

    esn_kernel<<<dim3(B_DIM), dim3(512), 0, stream>>>(x, W, out);
}

// Round 5
// 358.944 us; speedup vs baseline: 1.6537x; 1.6537x over previous
//
#include <hip/hip_runtime.h>

// ESN recurrence, MI355X — FOUR consumer waves with light-cone halo revision.
// (Third submit; two prior attempts died to container-acquisition flakes.
//  Deadlock audit: barrier counts match across branches (64+prologue), no
//  spin-polls, S exchange is phase-parity double-buffered and provably
//  race-free without timing assumptions.)
//
// THEORY: R1 (262 µs, 615 cyc/step) is issue-bound on ONE wave: 16 trans
// wave-ops/step (~16 cyc each quarter-rate) + ~200 cyc VALU/LDS/store issue,
// all on one SIMD. R2 proved per-step cross-wave sync costs ~300 cyc serial.
// Fix: 4 consumer waves (one per SIMD) each own a 128-elem core arc plus a
// halo window (256 slots = 4/lane). The stencil's speed-of-light is 1
// elem/step, so a valid halo lets each wave advance the 16 steps of a phase
// AUTONOMOUSLY (halo decays inward 1 slot/step; core stays exact, margin 48
// slots vs 16 needed). Halo refresh piggybacks on the phase barrier that
// already exists for the u double-buffer: each wave publishes its 128 core
// values to S[k&1][512] before the barrier and reloads its 256-slot window
// after — sync cost ~10 cyc/step instead of R2's 300. Decayed-halo garbage
// is tanh-bounded, never reaches the core, and is overwritten each refresh.
// Per-SIMD trans issue drops to 0.5x of R1.
//
// Producers: 4 waves (tid 256-511), each thread owns ring positions 2p,2p+1
// (W rows in registers), writes u as ds_write_b64, wave-uniform x loads.
// Barriers stay lgkm-only (consumer output stores remain in flight).

#define B_DIM 128
#define T_DIM 1024
#define D_DIM 8
#define R_DIM 512
#define NT    16            // timesteps per phase
#define NPHASE 64           // covers 1023 steps (last phase has 15)

#define SC   2.8853900817779268f   // 2*log2(e), folded into W and betas
#define BP_S (0.15f * SC)          // coeff on s[r+1], scaled
#define BM_S (0.85f * SC)          // coeff on s[r-1], scaled

__device__ __forceinline__ float esn_step(float L, float R, float u) {
    // pre' = 2log2e * (0.85 L + 0.15 R + u_raw); u already scaled.
    const float pre = fmaf(BM_S, L, fmaf(BP_S, R, u));
#if __has_builtin(__builtin_amdgcn_exp2f) && __has_builtin(__builtin_amdgcn_rcpf)
    const float e = __builtin_amdgcn_exp2f(pre);
    return fmaf(-2.0f, __builtin_amdgcn_rcpf(e + 1.0f), 1.0f);
#else
    const float e = exp2f(pre);
    return 1.0f - 2.0f / (e + 1.0f);
#endif
}

__device__ __forceinline__ void barrier_lds_only() {
    // LDS drain + barrier WITHOUT vmcnt(0): pending global stores stay in
    // flight across the barrier.
    asm volatile("s_waitcnt lgkmcnt(0)\n\ts_barrier" ::: "memory");
}

__global__ __launch_bounds__(512, 1) void esn_kernel(const float* __restrict__ x,
                                                     const float* __restrict__ W,
                                                     float* __restrict__ out) {
    __shared__ float ubuf[2][NT][R_DIM];   // u ring, 64 KB, plain layout
    __shared__ float S[2][R_DIM];          // state exchange, parity dbuf, 4 KB

    const int b   = blockIdx.x;
    const int tid = threadIdx.x;
    const float* xb = x + (size_t)b * T_DIM * D_DIM;

    // ---- Own W row (scaled) in registers for the prologue (r = tid).
    const float4 wa = *(const float4*)(W + tid * D_DIM);
    const float4 wc = *(const float4*)(W + tid * D_DIM + 4);
    const float w0 = wa.x * SC, w1 = wa.y * SC, w2 = wa.z * SC, w3 = wa.w * SC;
    const float w4 = wc.x * SC, w5 = wc.y * SC, w6 = wc.z * SC, w7 = wc.w * SC;

    // ---- Prologue: all 512 threads fill phase 0 (t = 1..16), r = tid.
#pragma unroll
    for (int j = 0; j < NT; ++j) {
        const float4 xa = *(const float4*)(xb + (j + 1) * D_DIM);
        const float4 xc = *(const float4*)(xb + (j + 1) * D_DIM + 4);
        float u = xa.x * w0;
        u = fmaf(xa.y, w1, u); u = fmaf(xa.z, w2, u); u = fmaf(xa.w, w3, u);
        u = fmaf(xc.x, w4, u); u = fmaf(xc.y, w5, u);
        u = fmaf(xc.z, w6, u); u = fmaf(xc.w, w7, u);
        ubuf[0][j][tid] = u;
    }
    __syncthreads();  // one full barrier before the loop (no stores pending yet)

    const int wid  = tid >> 6;
    const int lane = tid & 63;

    if (wid < 4) {
        // ============ consumers: 4 waves, window 256 slots (4/lane) ============
        // Wave w window base = 128w - 64 (mod 512); lane l owns ring positions
        // r0..r0+3, r0 = (128w - 64 + 4l) & 511 (groups never straddle the wrap
        // since r0 === 0 mod 4). Core (exact) slots are lanes 16..47.
        asm volatile("s_setprio 3" ::: "memory");
        const int lp = (lane + 63) & 63;   // left lane (source of slot0's L)
        const int ln = (lane + 1) & 63;    // right lane (source of slot3's R)
        const int r0 = (128 * wid - 64 + 4 * lane) & (R_DIM - 1);
        const bool core = (lane >= 16) && (lane < 48);

        float s0 = 0.0f, s1 = 0.0f, s2 = 0.0f, s3 = 0.0f;  // zeros incl. halo
        float* op = out + (size_t)b * T_DIM * R_DIM + r0;   // used by core lanes

        for (int k = 0; k < NPHASE; ++k) {
            const float* ub = &ubuf[k & 1][0][r0];
            const int steps = (k == NPHASE - 1) ? (1023 - NT * (NPHASE - 1)) : NT;
            float4 ua = *(const float4*)ub;
            for (int tl = 0; tl < steps; ++tl) {
                // prefetch next step's u (off the critical path)
                const int tn = (tl + 1 < steps) ? (tl + 1) : tl;
                const float4 na = *(const float4*)(ub + (size_t)tn * R_DIM);

                // intra-wave neighbor exchange (window-local; wrap lanes feed
                // already-decayed halo slots with bounded garbage — harmless)
                const float Lh = __shfl(s3, lp, 64);  // left lane's slot3
                const float Rh = __shfl(s0, ln, 64);  // right lane's slot0

                // interior first: overlap the bpermute latency
                const float n1 = esn_step(s0, s2, ua.y);
                const float n2 = esn_step(s1, s3, ua.z);
                const float n0 = esn_step(Lh, s1, ua.x);
                const float n3 = esn_step(s2, Rh, ua.w);

                if (core) *(float4*)op = make_float4(n0, n1, n2, n3);
                op += R_DIM;

                s0 = n0; s1 = n1; s2 = n2; s3 = n3;
                ua = na;
            }
            // Publish exact core state into this phase's parity buffer, then
            // refresh the full 256-slot window after the phase barrier.
            // Parity dbuf: publish(k+1) can never clobber an unread read(k).
            if (core) *(float4*)&S[k & 1][r0] = make_float4(s0, s1, s2, s3);
            barrier_lds_only();
            const float4 sv = *(const float4*)&S[k & 1][r0];
            s0 = sv.x; s1 = sv.y; s2 = sv.z; s3 = sv.w;
        }
    } else {
        // ================= producers (4 waves, tid 256-511) =================
        // Each thread owns ring positions 2p and 2p+1; W rows in registers,
        // zero LDS reads; x loads wave-uniform (broadcast); b64 LDS writes.
        asm volatile("s_setprio 0" ::: "memory");
        const int pid = tid - 256;          // 0..255
        const int pr  = 2 * pid;
        const float4 Aa = *(const float4*)(W + pr * D_DIM);
        const float4 Ac = *(const float4*)(W + pr * D_DIM + 4);
        const float4 Ba = *(const float4*)(W + (pr + 1) * D_DIM);
        const float4 Bc = *(const float4*)(W + (pr + 1) * D_DIM + 4);
        const float a0 = Aa.x * SC, a1 = Aa.y * SC, a2 = Aa.z * SC, a3 = Aa.w * SC;
        const float a4 = Ac.x * SC, a5 = Ac.y * SC, a6 = Ac.z * SC, a7 = Ac.w * SC;
        const float c0 = Ba.x * SC, c1 = Ba.y * SC, c2 = Ba.z * SC, c3 = Ba.w * SC;
        const float c4 = Bc.x * SC, c5 = Bc.y * SC, c6 = Bc.z * SC, c7 = Bc.w * SC;

        for (int k = 0; k < NPHASE; ++k) {
            if (k + 1 < NPHASE) {
                const int tb = NT * (k + 1) + 1;      // first t of next phase
                float* dst = &ubuf[(k + 1) & 1][0][0];
#pragma unroll
                for (int tl = 0; tl < NT; ++tl) {
                    const int t = tb + tl;
                    if (t < T_DIM) {
                        const float4 xa = *(const float4*)(xb + t * D_DIM);
                        const float4 xc = *(const float4*)(xb + t * D_DIM + 4);
                        float u0 = xa.x * a0;
                        u0 = fmaf(xa.y, a1, u0); u0 = fmaf(xa.z, a2, u0);
                        u0 = fmaf(xa.w, a3, u0); u0 = fmaf(xc.x, a4, u0);
                        u0 = fmaf(xc.y, a5, u0); u0 = fmaf(xc.z, a6, u0);
                        u0 = fmaf(xc.w, a7, u0);
                        float u1 = xa.x * c0;
                        u1 = fmaf(xa.y, c1, u1); u1 = fmaf(xa.z, c2, u1);
                        u1 = fmaf(xa.w, c3, u1); u1 = fmaf(xc.x, c4, u1);
                        u1 = fmaf(xc.y, c5, u1); u1 = fmaf(xc.z, c6, u1);
                        u1 = fmaf(xc.w, c7, u1);
                        *(float2*)&dst[tl * R_DIM + pr] = make_float2(u0, u1);
                    }
                }
            }
            barrier_lds_only();
        }
    }

    // Reference's final timestep is all zeros (d_out is poisoned 0xAA).
    out[(size_t)b * T_DIM * R_DIM + (size_t)(T_DIM - 1) * R_DIM + tid] = 0.0f;
}

extern "C" void kernel_launch(void* const* d_in, const int* in_sizes, int n_in,
                              void* d_out, int out_size, void* d_ws, size_t ws_size,
                              hipStream_t stream) {
    const float* x = (const float*)d_in[0];   // [B, T, D] fp32
    const float* W = (const float*)d_in[1];   // [R, D] fp32
    float* out = (float*)d_out;               // [B, T, R] fp32

    esn_kernel<<<dim3(B_DIM), dim3(512), 0, stream>>>(x, W, out);
}

// Round 6
// 347.600 us; speedup vs baseline: 1.7077x; 1.0326x over previous
//
#include <hip/hip_runtime.h>

// ESN recurrence, MI355X — row-local light-cone + DPP neighbor exchange.
//
// THEORY LADDER: R1 262 µs (1 consumer wave, issue-saturated). R5 ~155 µs
// (4 consumer waves, wave-level halo, per-step __shfl). Residual ~363
// cyc/step >> ~130 cyc issue => the per-step ds_bpermute latency chain
// (s -> bpermute ~60-120cy -> edge tanh -> next bpermute) is the limiter.
// THIS ROUND: neighbor exchange via DPP row shifts (row_shr:1 / row_shl:1,
// full-rate VALU, ~4 cyc, no LDS pipe). DPP can't cross 16-lane rows, so the
// light-cone is re-tiled at ROW granularity: each 16-lane row owns an
// independent 64-slot window = 32 core + 16 halo/side (margin 16 = NT).
// Row-edge lanes are halo edges; bound_ctrl=0 zeros are bounded garbage that
// decays inward 1 slot/step and never reaches the core. Zero fixups, zero
// per-step cross-lane LDS. Redundancy unchanged (2x), trans/wave/step
// unchanged (8), chain drops ~120cy -> ~40cy.
//
// Consumers: 4 waves x 4 rows x 16 lanes x 4 slots. Row (w,q) window base
// = 128w + 32q - 16 (mod 512). Core lanes: (lane&15) in [4,12).
// Halo refresh piggybacks on the existing per-16-step phase barrier via
// S[k&1][512] (parity double-buffered, race-free).
// Producers: 4 waves (tid 256-511), W rows in registers, wave-uniform x
// loads, ds_write_b64. Barriers lgkm-only (output stores stay in flight).

#define B_DIM 128
#define T_DIM 1024
#define D_DIM 8
#define R_DIM 512
#define NT    16            // timesteps per phase (== halo margin)
#define NPHASE 64           // covers 1023 steps (last phase has 15)

#define SC   2.8853900817779268f   // 2*log2(e), folded into W and betas
#define BP_S (0.15f * SC)          // coeff on s[r+1], scaled
#define BM_S (0.85f * SC)          // coeff on s[r-1], scaled

__device__ __forceinline__ float esn_step(float L, float R, float u) {
    // pre' = 2log2e * (0.85 L + 0.15 R + u_raw); u already scaled.
    const float pre = fmaf(BM_S, L, fmaf(BP_S, R, u));
#if __has_builtin(__builtin_amdgcn_exp2f) && __has_builtin(__builtin_amdgcn_rcpf)
    const float e = __builtin_amdgcn_exp2f(pre);
    return fmaf(-2.0f, __builtin_amdgcn_rcpf(e + 1.0f), 1.0f);
#else
    const float e = exp2f(pre);
    return 1.0f - 2.0f / (e + 1.0f);
#endif
}

// DPP row shifts: receive lane i-1 (row_shr:1 = 0x111) / lane i+1
// (row_shl:1 = 0x101) within each 16-lane row. bound_ctrl=1: row-edge
// lanes read 0.0f — they are halo edges, bounded garbage is fine.
__device__ __forceinline__ float dpp_prev(float v) {   // lane i <- lane i-1
    return __uint_as_float((unsigned)__builtin_amdgcn_update_dpp(
        0, (int)__float_as_uint(v), 0x111, 0xf, 0xf, true));
}
__device__ __forceinline__ float dpp_next(float v) {   // lane i <- lane i+1
    return __uint_as_float((unsigned)__builtin_amdgcn_update_dpp(
        0, (int)__float_as_uint(v), 0x101, 0xf, 0xf, true));
}

__device__ __forceinline__ void barrier_lds_only() {
    // LDS drain + barrier WITHOUT vmcnt(0): pending global stores stay in
    // flight across the barrier.
    asm volatile("s_waitcnt lgkmcnt(0)\n\ts_barrier" ::: "memory");
}

__global__ __launch_bounds__(512, 1) void esn_kernel(const float* __restrict__ x,
                                                     const float* __restrict__ W,
                                                     float* __restrict__ out) {
    __shared__ float ubuf[2][NT][R_DIM];   // u ring, 64 KB, plain layout
    __shared__ float S[2][R_DIM];          // state exchange, parity dbuf, 4 KB

    const int b   = blockIdx.x;
    const int tid = threadIdx.x;
    const float* xb = x + (size_t)b * T_DIM * D_DIM;

    // ---- Own W row (scaled) in registers for the prologue (r = tid).
    const float4 wa = *(const float4*)(W + tid * D_DIM);
    const float4 wc = *(const float4*)(W + tid * D_DIM + 4);
    const float w0 = wa.x * SC, w1 = wa.y * SC, w2 = wa.z * SC, w3 = wa.w * SC;
    const float w4 = wc.x * SC, w5 = wc.y * SC, w6 = wc.z * SC, w7 = wc.w * SC;

    // ---- Prologue: all 512 threads fill phase 0 (t = 1..16), r = tid.
#pragma unroll
    for (int j = 0; j < NT; ++j) {
        const float4 xa = *(const float4*)(xb + (j + 1) * D_DIM);
        const float4 xc = *(const float4*)(xb + (j + 1) * D_DIM + 4);
        float u = xa.x * w0;
        u = fmaf(xa.y, w1, u); u = fmaf(xa.z, w2, u); u = fmaf(xa.w, w3, u);
        u = fmaf(xc.x, w4, u); u = fmaf(xc.y, w5, u);
        u = fmaf(xc.z, w6, u); u = fmaf(xc.w, w7, u);
        ubuf[0][j][tid] = u;
    }
    __syncthreads();  // one full barrier before the loop (no stores pending yet)

    const int wid  = tid >> 6;
    const int lane = tid & 63;

    if (wid < 4) {
        // ======== consumers: 4 waves x 4 independent 16-lane rows ========
        // Row (w,q) window = 64 slots: base = 128w + 32q - 16 (mod 512).
        // Lane p (0..15) in the row owns ring positions r0..r0+3,
        // r0 = (base + 4p) & 511 (r0 % 4 == 0: float4 never straddles the
        // ring wrap). Core (exact through NT steps) lanes: p in [4,12).
        asm volatile("s_setprio 3" ::: "memory");
        const int q  = lane >> 4;          // row within wave
        const int p  = lane & 15;          // lane within row
        const int r0 = (128 * wid + 32 * q - 16 + 4 * p) & (R_DIM - 1);
        const bool core = (p >= 4) && (p < 12);

        float s0 = 0.0f, s1 = 0.0f, s2 = 0.0f, s3 = 0.0f;  // zeros incl. halo
        float* op = out + (size_t)b * T_DIM * R_DIM + r0;   // core lanes store

        for (int k = 0; k < NPHASE; ++k) {
            const float* ub = &ubuf[k & 1][0][r0];
            const int steps = (k == NPHASE - 1) ? (1023 - NT * (NPHASE - 1)) : NT;
            float4 ua = *(const float4*)ub;
            for (int tl = 0; tl < steps; ++tl) {
                // prefetch next step's u (off the critical path)
                const int tn = (tl + 1 < steps) ? (tl + 1) : tl;
                const float4 na = *(const float4*)(ub + (size_t)tn * R_DIM);

                // neighbor exchange on the VALU pipe (~4 cyc, no LDS):
                const float Lh = dpp_prev(s3);  // left lane's slot3
                const float Rh = dpp_next(s0);  // right lane's slot0

                const float n1 = esn_step(s0, s2, ua.y);
                const float n2 = esn_step(s1, s3, ua.z);
                const float n0 = esn_step(Lh, s1, ua.x);
                const float n3 = esn_step(s2, Rh, ua.w);

                if (core) *(float4*)op = make_float4(n0, n1, n2, n3);
                op += R_DIM;

                s0 = n0; s1 = n1; s2 = n2; s3 = n3;
                ua = na;
            }
            // Publish exact core state into this phase's parity buffer, then
            // refresh the full 64-slot row window after the phase barrier.
            if (core) *(float4*)&S[k & 1][r0] = make_float4(s0, s1, s2, s3);
            barrier_lds_only();
            const float4 sv = *(const float4*)&S[k & 1][r0];
            s0 = sv.x; s1 = sv.y; s2 = sv.z; s3 = sv.w;
        }
    } else {
        // ================= producers (4 waves, tid 256-511) =================
        // Each thread owns ring positions 2p and 2p+1; W rows in registers,
        // zero LDS reads; x loads wave-uniform (broadcast); b64 LDS writes.
        asm volatile("s_setprio 0" ::: "memory");
        const int pid = tid - 256;          // 0..255
        const int pr  = 2 * pid;
        const float4 Aa = *(const float4*)(W + pr * D_DIM);
        const float4 Ac = *(const float4*)(W + pr * D_DIM + 4);
        const float4 Ba = *(const float4*)(W + (pr + 1) * D_DIM);
        const float4 Bc = *(const float4*)(W + (pr + 1) * D_DIM + 4);
        const float a0 = Aa.x * SC, a1 = Aa.y * SC, a2 = Aa.z * SC, a3 = Aa.w * SC;
        const float a4 = Ac.x * SC, a5 = Ac.y * SC, a6 = Ac.z * SC, a7 = Ac.w * SC;
        const float c0 = Ba.x * SC, c1 = Ba.y * SC, c2 = Ba.z * SC, c3 = Ba.w * SC;
        const float c4 = Bc.x * SC, c5 = Bc.y * SC, c6 = Bc.z * SC, c7 = Bc.w * SC;

        for (int k = 0; k < NPHASE; ++k) {
            if (k + 1 < NPHASE) {
                const int tb = NT * (k + 1) + 1;      // first t of next phase
                float* dst = &ubuf[(k + 1) & 1][0][0];
#pragma unroll
                for (int tl = 0; tl < NT; ++tl) {
                    const int t = tb + tl;
                    if (t < T_DIM) {
                        const float4 xa = *(const float4*)(xb + t * D_DIM);
                        const float4 xc = *(const float4*)(xb + t * D_DIM + 4);
                        float u0 = xa.x * a0;
                        u0 = fmaf(xa.y, a1, u0); u0 = fmaf(xa.z, a2, u0);
                        u0 = fmaf(xa.w, a3, u0); u0 = fmaf(xc.x, a4, u0);
                        u0 = fmaf(xc.y, a5, u0); u0 = fmaf(xc.z, a6, u0);
                        u0 = fmaf(xc.w, a7, u0);
                        float u1 = xa.x * c0;
                        u1 = fmaf(xa.y, c1, u1); u1 = fmaf(xa.z, c2, u1);
                        u1 = fmaf(xa.w, c3, u1); u1 = fmaf(xc.x, c4, u1);
                        u1 = fmaf(xc.y, c5, u1); u1 = fmaf(xc.z, c6, u1);
                        u1 = fmaf(xc.w, c7, u1);
                        *(float2*)&dst[tl * R_DIM + pr] = make_float2(u0, u1);
                    }
                }
            }
            barrier_lds_only();
        }
    }

    // Reference's final timestep is all zeros (d_out is poisoned 0xAA).
    out[(size_t)b * T_DIM * R_DIM + (size_t)(T_DIM - 1) * R_DIM + tid] = 0.0f;
}

extern "C" void kernel_launch(void* const* d_in, const int* in_sizes, int n_in,
                              void* d_out, int out_size, void* d_ws, size_t ws_size,
                              hipStream_t stream) {
    const float* x = (const float*)d_in[0];   // [B, T, D] fp32
    const float* W = (const float*)d_in[1];   // [R, D] fp32
    float* out = (float*)d_out;               // [B, T, R] fp32

    esn_kernel<<<dim3(B_DIM), dim3(512), 0, stream>>>(x, W, out);
}